// Round 15
// baseline (1274.213 us; speedup 1.0000x reference)
//
#include <hip/hip_runtime.h>
#include <math.h>

#define N 1024
#define F 4096
#define NLAYERS 24
#define VOCAB 50277
#define GRID 256
#define BLOCK 512   // wave0 = sweeper/producer (no weights), waves 1-7 = workers

// ws floats: r2buf[N]@0; sxacc[2][4][N]@N; facc[2][4][N]@N+8192
#define SXACC_OFF N
#define FACC_OFF (N + 8192)
#define BAR_OFF_BYTES 69632
#define LINE 16
#define BAR_DWORDS (256 * LINE)
#define WS_CLEAR_BYTES (BAR_OFF_BYTES + BAR_DWORDS * 4)

#define DRAIN(K) asm volatile("s_waitcnt vmcnt(" #K ") lgkmcnt(0)" ::: "memory")

__device__ __forceinline__ float dot4(float4 a, float4 b) {
  return fmaf(a.x, b.x, fmaf(a.y, b.y, fmaf(a.z, b.z, a.w * b.w)));
}
__device__ __forceinline__ float wred(float v) {
#pragma unroll
  for (int o = 32; o > 0; o >>= 1) v += __shfl_down(v, o, 64);
  return v;
}
__device__ __forceinline__ float bfly(float v) {
#pragma unroll
  for (int o = 1; o < 64; o <<= 1) v += __shfl_xor(v, o, 64);
  return v;
}
__device__ __forceinline__ float sigmoidf(float x) { return 1.f / (1.f + expf(-x)); }

__device__ __forceinline__ float2 ld_c2(const float* p) {
  unsigned long long u = __hip_atomic_load((const unsigned long long*)p,
                                           __ATOMIC_RELAXED, __HIP_MEMORY_SCOPE_AGENT);
  float2 f;
  f.x = __uint_as_float((unsigned)u);
  f.y = __uint_as_float((unsigned)(u >> 32));
  return f;
}
__device__ __forceinline__ void st_c(float* p, float v) {
  __hip_atomic_store(p, v, __ATOMIC_RELAXED, __HIP_MEMORY_SCOPE_AGENT);
}
__device__ __forceinline__ unsigned ld_cu(const unsigned* p) {
  return __hip_atomic_load(p, __ATOMIC_RELAXED, __HIP_MEMORY_SCOPE_AGENT);
}
__device__ __forceinline__ void st_cu(unsigned* p, unsigned v) {
  __hip_atomic_store(p, v, __ATOMIC_RELAXED, __HIP_MEMORY_SCOPE_AGENT);
}

__device__ __forceinline__ void lbar() {
  asm volatile("s_waitcnt lgkmcnt(0)" ::: "memory");
  __builtin_amdgcn_s_barrier();
}

// block barrier + wave0 publishes flag (caller already drained what must drain)
__device__ __forceinline__ void arrive_flag(unsigned* arr, unsigned gen, int blk,
                                            int tid) {
  __builtin_amdgcn_s_barrier();
  if (tid == 0) st_cu(arr + blk * LINE, gen);
}
// wave0 (vmem-clean) sweeps all 256 flags
__device__ __forceinline__ void sweep(const unsigned* arr, unsigned gen, int lane) {
  for (;;) {
    bool ok = true;
#pragma unroll
    for (int i = 0; i < 4; ++i)
      ok &= (ld_cu(arr + (lane * 4 + i) * LINE) >= gen);
    if (__all(ok)) break;
    __builtin_amdgcn_s_sleep(1);
  }
  asm volatile("" ::: "memory");
}
__device__ __forceinline__ void set_gen(unsigned* sg, unsigned gen) {
  asm volatile("s_waitcnt lgkmcnt(0)" ::: "memory");
  __hip_atomic_store(sg, gen, __ATOMIC_RELEASE, __HIP_MEMORY_SCOPE_WORKGROUP);
}
__device__ __forceinline__ void wait_gen(const unsigned* sg, unsigned gen) {
  while (__hip_atomic_load(sg, __ATOMIC_ACQUIRE, __HIP_MEMORY_SCOPE_WORKGROUP) < gen)
    __builtin_amdgcn_s_sleep(1);
  asm volatile("" ::: "memory");
}

// redundant-per-wave LayerNorm of 16 lane-columns in q[4]
__device__ __forceinline__ void ln16(float4* q, const float* __restrict__ w,
                                     const float* __restrict__ b, int lane) {
  float s = 0.f, sq = 0.f;
#pragma unroll
  for (int k = 0; k < 4; ++k) {
    s += q[k].x + q[k].y + q[k].z + q[k].w;
    sq += dot4(q[k], q[k]);
  }
  s = bfly(s);
  sq = bfly(sq);
  float mu = s * (1.f / N);
  float rstd = rsqrtf(sq * (1.f / N) - mu * mu + 1e-5f);
#pragma unroll
  for (int k = 0; k < 4; ++k) {
    float4 w4 = ((const float4*)w)[(k << 6) + lane];
    float4 b4 = ((const float4*)b)[(k << 6) + lane];
    q[k].x = (q[k].x - mu) * rstd * w4.x + b4.x;
    q[k].y = (q[k].y - mu) * rstd * w4.y + b4.y;
    q[k].z = (q[k].z - mu) * rstd * w4.z + b4.z;
    q[k].w = (q[k].w - mu) * rstd * w4.w + b4.w;
  }
}

__device__ __forceinline__ float4 mix4(float4 a, float4 s, float4 m) {
  float4 r;
  r.x = a.x * m.x + s.x * (1.f - m.x);
  r.y = a.y * m.y + s.y * (1.f - m.y);
  r.z = a.z * m.z + s.z * (1.f - m.z);
  r.w = a.w * m.w + s.w * (1.f - m.w);
  return r;
}

__device__ __forceinline__ void wkv1(float k, float v, float r, float aa, float bb,
                                     float pp, float tf, float td, float& rab,
                                     float& naa, float& nbb, float& npp) {
  float ww = tf + k;
  float q = fmaxf(pp, ww);
  float e1 = expf(pp - q);
  float e2 = expf(ww - q);
  float a = e1 * aa + e2 * v;
  float b = e1 * bb + e2;
  rab = r * a / b;
  float ww2 = pp + td;
  float q2 = fmaxf(ww2, k);
  float f1 = expf(ww2 - q2);
  float f2 = expf(k - q2);
  naa = f1 * aa + f2 * v;
  nbb = f1 * bb + f2;
  npp = q2;
}

__global__ __launch_bounds__(BLOCK, 1) void k_rwkv(
    const int* __restrict__ ctx, const float* __restrict__ state,
    const float* __restrict__ emb, const float* __restrict__ ln0w,
    const float* __restrict__ ln0b, const float* __restrict__ ln1w,
    const float* __restrict__ ln1b, const float* __restrict__ amk,
    const float* __restrict__ amv, const float* __restrict__ amr,
    const float* __restrict__ tf, const float* __restrict__ td,
    const float* __restrict__ kw, const float* __restrict__ vw,
    const float* __restrict__ rw, const float* __restrict__ ow,
    const float* __restrict__ ln2w, const float* __restrict__ ln2b,
    const float* __restrict__ fmk, const float* __restrict__ fmr,
    const float* __restrict__ fkw, const float* __restrict__ fvw,
    const float* __restrict__ frw, const float* __restrict__ lnoutw,
    const float* __restrict__ lnoutb, const float* __restrict__ head,
    float* __restrict__ out, float* __restrict__ ws, unsigned* __restrict__ bar) {
  __shared__ __align__(16) float s_vx[N];   // layer input x (wave0-produced)
  __shared__ __align__(16) float s_sx[N];   // sx (wave0-produced)
  __shared__ __align__(16) float s_ex[16];  // k[4],v[4],r[4],rab[4]
  __shared__ __align__(16) float s_kk[16];
  __shared__ unsigned s_flag;

  const int tid = threadIdx.x;
  const int lane = tid & 63;
  const int wid = tid >> 6;
  const bool work = (wid > 0);
  const int blk = blockIdx.x;
  const size_t nn = (size_t)N * N;

  if (tid == 0) s_flag = 0;
  __syncthreads();

  float* logits = out;
  float* st_out = out + VOCAB;
  float* r2buf = ws;
  float* sxacc = ws + SXACC_OFF;  // [2][4][N]
  float* facc = ws + FACC_OFF;    // [2][4][N]
  unsigned bgen = 0, fgen = 0;

  // XCD-team col ownership (4 blocks share a 16-col panel)
  const int xcd = blk & 7, sgrp = blk >> 3;
  const int jm = sgrp & 3, gg = sgrp >> 2;
  const int c0 = (((xcd + (gg << 3)) << 4) + (jm << 2));

  const int wl = (wid - 1) * 64 + lane;  // worker flat lane [0,448)
  // AB rows (0-3 kw, 4-7 vw, 8-11 rw): waves 1-6 own rows wid-1 and wid+5
  const int rI = wid - 1, rJ = wid + 5;
  const bool hasAB = (wid >= 1 && wid <= 6);
  // C rows (0-15 fkw, 16-19 frw): waves 1-6 own 3(wid-1)..+2, wave7 owns 18,19
  const int iA = (wid <= 6) ? 3 * (wid - 1) : 18;
  const int iB = iA + 1;
  const int iC = iA + 2;  // only waves 1-6
  const bool w7 = (wid == 7);
  // panel rows: waves1-6: 2/lane; wave7: 4/lane
  const int rv0 = work ? ((wl + (blk << 2)) & (N - 1)) : 0;
  const int rv1 = work ? ((wl + 448 + (blk << 2)) & (N - 1)) : 0;
  const int rv2 = w7 ? ((896 + lane + (blk << 2)) & (N - 1)) : 0;
  const int rv3 = w7 ? ((960 + lane + (blk << 2)) & (N - 1)) : 0;

  float4 paI[4], paJ[4], powr0, powr1, powr2, powr3;
  float4 pkA[4], pkB[4], pkC[4], pf0[4], pf1[4], pf2[4], pf3[4];
  float kaa = 0.f, kbb = 0.f, kpp = 0.f, ktf = 0.f, ktd = 0.f;

  auto parow = [&](int r, int lc) -> const float* {
    int m = r >> 2;
    const float* base = (m == 0) ? kw : (m == 1) ? vw : rw;
    return base + (size_t)lc * nn + (size_t)(c0 + (r & 3)) * N;
  };
  auto pcrow = [&](int i, int lc) -> const float* {
    return (i < 16) ? fkw + (size_t)lc * F * N + (size_t)((blk << 4) + i) * N
                    : frw + (size_t)lc * nn + (size_t)((blk << 2) + (i - 16)) * N;
  };
  // pfA: waves1-6 = 10 loads; wave7 = 4 loads
  auto pfA = [&](int lc) {
    const float* owl = ow + (size_t)lc * nn;
    if (hasAB) {
      const float* WI = parow(rI, lc);
#pragma unroll
      for (int k = 0; k < 4; ++k) paI[k] = ((const float4*)WI)[(k << 6) + lane];
      const float* WJ = parow(rJ, lc);
#pragma unroll
      for (int k = 0; k < 4; ++k) paJ[k] = ((const float4*)WJ)[(k << 6) + lane];
      powr0 = *(const float4*)(owl + (size_t)rv0 * N + c0);
      powr1 = *(const float4*)(owl + (size_t)rv1 * N + c0);
    } else {
      powr0 = *(const float4*)(owl + (size_t)rv0 * N + c0);
      powr1 = *(const float4*)(owl + (size_t)rv1 * N + c0);
      powr2 = *(const float4*)(owl + (size_t)rv2 * N + c0);
      powr3 = *(const float4*)(owl + (size_t)rv3 * N + c0);
    }
  };
  // pfC: waves1-6 = 20 loads; wave7 = 16 loads
  auto pfC = [&](int lc) {
    const float* fvb = fvw + (size_t)lc * N * F + (blk << 4);
    const float* WA = pcrow(iA, lc);
#pragma unroll
    for (int k = 0; k < 4; ++k) pkA[k] = ((const float4*)WA)[(k << 6) + lane];
    const float* WB = pcrow(iB, lc);
#pragma unroll
    for (int k = 0; k < 4; ++k) pkB[k] = ((const float4*)WB)[(k << 6) + lane];
    if (hasAB) {
      const float* WC = pcrow(iC, lc);
#pragma unroll
      for (int k = 0; k < 4; ++k) pkC[k] = ((const float4*)WC)[(k << 6) + lane];
#pragma unroll
      for (int i = 0; i < 4; ++i) pf0[i] = ((const float4*)(fvb + (size_t)rv0 * F))[i];
#pragma unroll
      for (int i = 0; i < 4; ++i) pf1[i] = ((const float4*)(fvb + (size_t)rv1 * F))[i];
    } else {
#pragma unroll
      for (int i = 0; i < 4; ++i) pf0[i] = ((const float4*)(fvb + (size_t)rv0 * F))[i];
#pragma unroll
      for (int i = 0; i < 4; ++i) pf1[i] = ((const float4*)(fvb + (size_t)rv1 * F))[i];
#pragma unroll
      for (int i = 0; i < 4; ++i) pf2[i] = ((const float4*)(fvb + (size_t)rv2 * F))[i];
#pragma unroll
      for (int i = 0; i < 4; ++i) pf3[i] = ((const float4*)(fvb + (size_t)rv3 * F))[i];
    }
  };

  // ================= pre-loop =================
  ++fgen;
  if (work) {
    pfA(0);
    wait_gen(&s_flag, fgen);
  } else {
    // wave0: x0 = LN0(0.2*(4*emb[t1]+emb[t0])) into s_vx
    int t1 = ctx[1], t0c = ctx[0];
    const float2* e1p = (const float2*)(emb + (size_t)t1 * N);
    const float2* e0p = (const float2*)(emb + (size_t)t0c * N);
    float2 xv[8];
#pragma unroll
    for (int j = 0; j < 8; ++j) {
      float2 a = e1p[lane * 8 + j], b = e0p[lane * 8 + j];
      xv[j].x = (a.x * 4.f + b.x) * 0.2f;
      xv[j].y = (a.y * 4.f + b.y) * 0.2f;
    }
    float s = 0.f, sq = 0.f;
#pragma unroll
    for (int j = 0; j < 8; ++j) { s += xv[j].x + xv[j].y; sq += xv[j].x * xv[j].x + xv[j].y * xv[j].y; }
    s = bfly(s); sq = bfly(sq);
    float mu = s * (1.f / N);
    float rs = rsqrtf(sq * (1.f / N) - mu * mu + 1e-5f);
#pragma unroll
    for (int j = 0; j < 8; ++j) {
      float2 w2 = ((const float2*)ln0w)[lane * 8 + j];
      float2 b2 = ((const float2*)ln0b)[lane * 8 + j];
      float2 o;
      o.x = (xv[j].x - mu) * rs * w2.x + b2.x;
      o.y = (xv[j].y - mu) * rs * w2.y + b2.y;
      ((float2*)s_vx)[lane * 8 + j] = o;
    }
    set_gen(&s_flag, fgen);
    if (lane < 4) {
      int ii = c0 + lane;
      kaa = state[2 * N + ii];
      kbb = state[3 * N + ii];
      kpp = state[4 * N + ii];
      ktf = tf[ii];
      ktd = td[ii];
    }
  }

  for (int l = 0; l < NLAYERS; ++l) {
    const int p = l & 1;
    float* sto = st_out + (size_t)l * 5 * N;
    const float* st_l = state + (size_t)l * 5 * N;

    // ================= AB body =================
    if (work) {
      float4 xl[4];
#pragma unroll
      for (int k = 0; k < 4; ++k) xl[k] = ((const float4*)s_vx)[(k << 6) + lane];
      ln16(xl, ln1w + l * N, ln1b + l * N, lane);
      if (blk == 4 && wid == 1) {
#pragma unroll
        for (int k = 0; k < 4; ++k) ((float4*)(sto + N))[(k << 6) + lane] = xl[k];
      }
      if (hasAB) {
        int mI = rI >> 2, mJ = rJ >> 2;
        float dI = 0.f, dJ = 0.f;
#pragma unroll
        for (int k = 0; k < 4; ++k) {
          float4 s1 = ((const float4*)(st_l + N))[(k << 6) + lane];
          float4 mk = mix4(xl[k], s1, ((const float4*)(amk + l * N))[(k << 6) + lane]);
          float4 mv = mix4(xl[k], s1, ((const float4*)(amv + l * N))[(k << 6) + lane]);
          float4 mr = mix4(xl[k], s1, ((const float4*)(amr + l * N))[(k << 6) + lane]);
          float4 mmI = (mI == 0) ? mk : ((mI == 1) ? mv : mr);
          float4 mmJ = (mJ == 0) ? mk : ((mJ == 1) ? mv : mr);
          dI += dot4(paI[k], mmI);
          dJ += dot4(paJ[k], mmJ);
        }
        dI = wred(dI);
        dJ = wred(dJ);
        if (lane == 0) {
          s_ex[rI] = (rI >= 8) ? sigmoidf(dI) : dI;
          s_ex[rJ] = (rJ >= 8) ? sigmoidf(dJ) : dJ;
        }
      }
    }
    lbar();
    if (!work && lane < 4) {
      float rab, naa, nbb, npp;
      wkv1(s_ex[lane], s_ex[4 + lane], s_ex[8 + lane], kaa, kbb, kpp, ktf, ktd,
           rab, naa, nbb, npp);
      int ii = c0 + lane;
      sto[2 * N + ii] = naa;
      sto[3 * N + ii] = nbb;
      sto[4 * N + ii] = npp;
      s_ex[12 + lane] = rab;
    }
    lbar();
    if (work) {
      float4 rab4 = *((const float4*)(s_ex + 12));
      float* sxa = sxacc + p * 4096 + (blk & 3) * N;
      unsafeAtomicAdd(sxa + rv0, dot4(powr0, rab4));
      unsafeAtomicAdd(sxa + rv1, dot4(powr1, rab4));
      if (w7) {
        unsafeAtomicAdd(sxa + rv2, dot4(powr2, rab4));
        unsafeAtomicAdd(sxa + rv3, dot4(powr3, rab4));
      }
      pfC(l);  // prefetch C weights; stream across the barrier
      if (w7) DRAIN(16);
      else DRAIN(20);
    } else {
      DRAIN(0);
    }
    arrive_flag(bar, ++bgen, blk, tid);
    ++fgen;
    // ===== window-SX: wave0 sweeps + produces sx; workers' prefetch flies =====
    if (!work) {
      sweep(bar, bgen, lane);
      const float* sb = sxacc + p * 4096;
#pragma unroll
      for (int j = 0; j < 8; ++j) {
        int idx = lane * 16 + 2 * j;
        float ax = 0.f, ay = 0.f;
#pragma unroll
        for (int c = 0; c < 4; ++c) {
          float2 t2 = ld_c2(sb + c * N + idx);
          ax += t2.x;
          ay += t2.y;
        }
        float2 x2 = ((const float2*)s_vx)[lane * 8 + j];
        float2 o;
        o.x = x2.x + ax;
        o.y = x2.y + ay;
        ((float2*)s_sx)[lane * 8 + j] = o;
      }
      set_gen(&s_flag, fgen);
      if (lane < 16) st_c(facc + (1 - p) * 4096 + blk * 16 + lane, 0.f);
    } else {
      wait_gen(&s_flag, fgen);
    }

    // ================= C body =================
    if (work) {
      float4 x2q[4];
#pragma unroll
      for (int k = 0; k < 4; ++k) x2q[k] = ((const float4*)s_sx)[(k << 6) + lane];
      ln16(x2q, ln2w + l * N, ln2b + l * N, lane);
      if (blk == 5 && wid == 1) {
#pragma unroll
        for (int k = 0; k < 4; ++k) ((float4*)sto)[(k << 6) + lane] = x2q[k];
      }
      float dA = 0.f, dB = 0.f, dC = 0.f;
#pragma unroll
      for (int k = 0; k < 4; ++k) {
        float4 s0 = ((const float4*)st_l)[(k << 6) + lane];
        float4 mk = mix4(x2q[k], s0, ((const float4*)(fmk + l * N))[(k << 6) + lane]);
        float4 mr = mix4(x2q[k], s0, ((const float4*)(fmr + l * N))[(k << 6) + lane]);
        dA += dot4(pkA[k], (iA < 16) ? mk : mr);
        dB += dot4(pkB[k], (iB < 16) ? mk : mr);
        if (hasAB) dC += dot4(pkC[k], (iC < 16) ? mk : mr);
      }
      dA = wred(dA);
      dB = wred(dB);
      if (hasAB) dC = wred(dC);
      if (lane == 0) {
        if (iA < 16) { float t = fmaxf(dA, 0.f); s_kk[iA] = t * t; }
        else st_c(r2buf + (blk << 2) + (iA - 16), sigmoidf(dA));
        if (iB < 16) { float t = fmaxf(dB, 0.f); s_kk[iB] = t * t; }
        else st_c(r2buf + (blk << 2) + (iB - 16), sigmoidf(dB));
        if (hasAB) {
          if (iC < 16) { float t = fmaxf(dC, 0.f); s_kk[iC] = t * t; }
          else st_c(r2buf + (blk << 2) + (iC - 16), sigmoidf(dC));
        }
      }
    }
    lbar();
    const bool ldav = (l + 1 < NLAYERS);
    if (work) {
      float4 K0 = ((const float4*)s_kk)[0];
      float4 K1 = ((const float4*)s_kk)[1];
      float4 K2 = ((const float4*)s_kk)[2];
      float4 K3 = ((const float4*)s_kk)[3];
      float* fc = facc + p * 4096 + (blk & 3) * N;
      unsafeAtomicAdd(fc + rv0, dot4(pf0[0], K0) + dot4(pf0[1], K1) +
                                    dot4(pf0[2], K2) + dot4(pf0[3], K3));
      unsafeAtomicAdd(fc + rv1, dot4(pf1[0], K0) + dot4(pf1[1], K1) +
                                    dot4(pf1[2], K2) + dot4(pf1[3], K3));
      if (w7) {
        unsafeAtomicAdd(fc + rv2, dot4(pf2[0], K0) + dot4(pf2[1], K1) +
                                      dot4(pf2[2], K2) + dot4(pf2[3], K3));
        unsafeAtomicAdd(fc + rv3, dot4(pf3[0], K0) + dot4(pf3[1], K1) +
                                      dot4(pf3[2], K2) + dot4(pf3[3], K3));
      }
      if (ldav) {
        pfA(l + 1);  // prefetch next AB weights; stream across the barrier
        if (w7) DRAIN(4);
        else DRAIN(10);
      } else {
        DRAIN(0);
      }
    } else {
      DRAIN(0);
    }
    arrive_flag(bar, ++bgen, blk, tid);
    ++fgen;
    // ===== window-X(l+1): wave0 sweeps + produces x =====
    if (!work) {
      sweep(bar, bgen, lane);
      const float* fb = facc + p * 4096;
#pragma unroll
      for (int j = 0; j < 8; ++j) {
        int idx = lane * 16 + 2 * j;
        float ax = 0.f, ay = 0.f;
#pragma unroll
        for (int c = 0; c < 4; ++c) {
          float2 t2 = ld_c2(fb + c * N + idx);
          ax += t2.x;
          ay += t2.y;
        }
        float2 r2 = ld_c2(r2buf + idx);
        float2 sx2 = ((const float2*)s_sx)[lane * 8 + j];
        float2 o;
        o.x = sx2.x + r2.x * ax;
        o.y = sx2.y + r2.y * ay;
        ((float2*)s_vx)[lane * 8 + j] = o;
      }
      set_gen(&s_flag, fgen);
      if (ldav) {
        if (lane < 16) st_c(sxacc + p * 4096 + blk * 16 + lane, 0.f);
        if (lane < 4) {
          const float* stn = state + (size_t)(l + 1) * 5 * N;
          int ii = c0 + lane;
          kaa = stn[2 * N + ii];
          kbb = stn[3 * N + ii];
          kpp = stn[4 * N + ii];
          ktf = tf[(l + 1) * N + ii];
          ktd = td[(l + 1) * N + ii];
        }
      }
    } else {
      wait_gen(&s_flag, fgen);
    }
  }

  // ================= head: logits = head @ LN(s_vx) =================
  {
    float4 xf[4];
#pragma unroll
    for (int k = 0; k < 4; ++k) xf[k] = ((const float4*)s_vx)[(k << 6) + lane];
    ln16(xf, lnoutw, lnoutb, lane);
    for (int base = (blk * 8 + wid) * 4; base < VOCAB; base += GRID * 8 * 4) {
      float4 h[4][4];
#pragma unroll
      for (int rr = 0; rr < 4; ++rr) {
        int row = base + rr;
        if (row < VOCAB) {
          const float4* hp = (const float4*)(head + (size_t)row * N);
#pragma unroll
          for (int k = 0; k < 4; ++k) h[rr][k] = hp[(k << 6) + lane];
        }
      }
#pragma unroll
      for (int rr = 0; rr < 4; ++rr) {
        int row = base + rr;
        if (row < VOCAB) {
          float d = 0.f;
#pragma unroll
          for (int k = 0; k < 4; ++k) d += dot4(h[rr][k], xf[k]);
          d = wred(d);
          if (lane == 0) logits[row] = d;
        }
      }
    }
  }
}

extern "C" void kernel_launch(void* const* d_in, const int* in_sizes, int n_in,
                              void* d_out, int out_size, void* d_ws, size_t ws_size,
                              hipStream_t stream) {
  const int* ctx = (const int*)d_in[0];
  const float* state = (const float*)d_in[1];
  const float* emb = (const float*)d_in[2];
  const float* ln0w = (const float*)d_in[3];
  const float* ln0b = (const float*)d_in[4];
  const float* ln1w = (const float*)d_in[5];
  const float* ln1b = (const float*)d_in[6];
  const float* amk = (const float*)d_in[7];
  const float* amv = (const float*)d_in[8];
  const float* amr = (const float*)d_in[9];
  const float* tf = (const float*)d_in[10];
  const float* td = (const float*)d_in[11];
  const float* kw = (const float*)d_in[12];
  const float* vw = (const float*)d_in[13];
  const float* rw = (const float*)d_in[14];
  const float* ow = (const float*)d_in[15];
  const float* ln2w = (const float*)d_in[16];
  const float* ln2b = (const float*)d_in[17];
  const float* fmk = (const float*)d_in[18];
  const float* fmr = (const float*)d_in[19];
  const float* fkw = (const float*)d_in[20];
  const float* fvw = (const float*)d_in[21];
  const float* frw = (const float*)d_in[22];
  const float* lnoutw = (const float*)d_in[23];
  const float* lnoutb = (const float*)d_in[24];
  const float* head = (const float*)d_in[25];
  float* out = (float*)d_out;
  float* ws = (float*)d_ws;
  unsigned* bar = (unsigned*)((char*)d_ws + BAR_OFF_BYTES);

  hipMemsetAsync(d_ws, 0, WS_CLEAR_BYTES, stream);

  void* args[] = {&ctx, &state, &emb, &ln0w, &ln0b, &ln1w, &ln1b,
                  &amk, &amv, &amr, &tf, &td, &kw, &vw, &rw, &ow,
                  &ln2w, &ln2b, &fmk, &fmr, &fkw, &fvw, &frw,
                  &lnoutw, &lnoutb, &head, &out, &ws, &bar};
  hipLaunchCooperativeKernel((const void*)k_rwkv, dim3(GRID), dim3(BLOCK),
                             args, 0, stream);
}

// Round 16
// 989.347 us; speedup vs baseline: 1.2879x; 1.2879x over previous
//
#include <hip/hip_runtime.h>
#include <math.h>

#define N 1024
#define F 4096
#define NLAYERS 24
#define VOCAB 50277
#define GRID 256
#define BLOCK 512   // wave0 = clean sweeper (+2 panel rows), waves 1-7 = row workers

// ws floats: r2buf[N]@0; sxacc[2][4][N]@N; facc[2][4][N]@N+8192
#define SXACC_OFF N
#define FACC_OFF (N + 8192)
#define BAR_OFF_BYTES 69632
#define LINE 16
#define BAR_DWORDS (256 * LINE)
#define WS_CLEAR_BYTES (BAR_OFF_BYTES + BAR_DWORDS * 4)

#define DRAIN(K) asm volatile("s_waitcnt vmcnt(" #K ") lgkmcnt(0)" ::: "memory")

__device__ __forceinline__ float dot4(float4 a, float4 b) {
  return fmaf(a.x, b.x, fmaf(a.y, b.y, fmaf(a.z, b.z, a.w * b.w)));
}
__device__ __forceinline__ float wred(float v) {
#pragma unroll
  for (int o = 32; o > 0; o >>= 1) v += __shfl_down(v, o, 64);
  return v;
}
__device__ __forceinline__ float bfly(float v) {
#pragma unroll
  for (int o = 1; o < 64; o <<= 1) v += __shfl_xor(v, o, 64);
  return v;
}
__device__ __forceinline__ float sigmoidf(float x) { return 1.f / (1.f + expf(-x)); }

__device__ __forceinline__ float2 ld_c2(const float* p) {
  unsigned long long u = __hip_atomic_load((const unsigned long long*)p,
                                           __ATOMIC_RELAXED, __HIP_MEMORY_SCOPE_AGENT);
  float2 f;
  f.x = __uint_as_float((unsigned)u);
  f.y = __uint_as_float((unsigned)(u >> 32));
  return f;
}
__device__ __forceinline__ void st_c(float* p, float v) {
  __hip_atomic_store(p, v, __ATOMIC_RELAXED, __HIP_MEMORY_SCOPE_AGENT);
}
__device__ __forceinline__ unsigned ld_cu(const unsigned* p) {
  return __hip_atomic_load(p, __ATOMIC_RELAXED, __HIP_MEMORY_SCOPE_AGENT);
}
__device__ __forceinline__ void st_cu(unsigned* p, unsigned v) {
  __hip_atomic_store(p, v, __ATOMIC_RELAXED, __HIP_MEMORY_SCOPE_AGENT);
}

__device__ __forceinline__ void lbar() {
  asm volatile("s_waitcnt lgkmcnt(0)" ::: "memory");
  __builtin_amdgcn_s_barrier();
}

// block barrier + flag (caller drained what must drain via DRAIN)
__device__ __forceinline__ void arrive_flag(unsigned* arr, unsigned gen, int blk,
                                            int tid) {
  __builtin_amdgcn_s_barrier();
  if (tid == 0) st_cu(arr + blk * LINE, gen);
}
// wave0 (vmem-clean): sweep all 256 flags, signal workers via LDS
__device__ __forceinline__ void sweep_signal(const unsigned* arr, unsigned gen,
                                             int lane, unsigned* s_gen) {
  for (;;) {
    bool ok = true;
#pragma unroll
    for (int i = 0; i < 4; ++i)
      ok &= (ld_cu(arr + (lane * 4 + i) * LINE) >= gen);
    if (__all(ok)) break;
    __builtin_amdgcn_s_sleep(1);
  }
  __hip_atomic_store(s_gen, gen, __ATOMIC_RELEASE, __HIP_MEMORY_SCOPE_WORKGROUP);
}
// workers: spin on LDS flag (pre-issued vector prefetch stays in flight)
__device__ __forceinline__ void lds_wait(const unsigned* s_gen, unsigned gen) {
  while (__hip_atomic_load(s_gen, __ATOMIC_ACQUIRE, __HIP_MEMORY_SCOPE_WORKGROUP) < gen)
    __builtin_amdgcn_s_sleep(1);
  asm volatile("" ::: "memory");
}

// redundant-per-wave LayerNorm of 16 lane-columns in q[4]
__device__ __forceinline__ void ln16(float4* q, const float* __restrict__ w,
                                     const float* __restrict__ b, int lane) {
  float s = 0.f, sq = 0.f;
#pragma unroll
  for (int k = 0; k < 4; ++k) {
    s += q[k].x + q[k].y + q[k].z + q[k].w;
    sq += dot4(q[k], q[k]);
  }
  s = bfly(s);
  sq = bfly(sq);
  float mu = s * (1.f / N);
  float rstd = rsqrtf(sq * (1.f / N) - mu * mu + 1e-5f);
#pragma unroll
  for (int k = 0; k < 4; ++k) {
    float4 w4 = ((const float4*)w)[(k << 6) + lane];
    float4 b4 = ((const float4*)b)[(k << 6) + lane];
    q[k].x = (q[k].x - mu) * rstd * w4.x + b4.x;
    q[k].y = (q[k].y - mu) * rstd * w4.y + b4.y;
    q[k].z = (q[k].z - mu) * rstd * w4.z + b4.z;
    q[k].w = (q[k].w - mu) * rstd * w4.w + b4.w;
  }
}

__device__ __forceinline__ float4 mix4(float4 a, float4 s, float4 m) {
  float4 r;
  r.x = a.x * m.x + s.x * (1.f - m.x);
  r.y = a.y * m.y + s.y * (1.f - m.y);
  r.z = a.z * m.z + s.z * (1.f - m.z);
  r.w = a.w * m.w + s.w * (1.f - m.w);
  return r;
}

__device__ __forceinline__ void wkv1(float k, float v, float r, float aa, float bb,
                                     float pp, float tf, float td, float& rab,
                                     float& naa, float& nbb, float& npp) {
  float ww = tf + k;
  float q = fmaxf(pp, ww);
  float e1 = expf(pp - q);
  float e2 = expf(ww - q);
  float a = e1 * aa + e2 * v;
  float b = e1 * bb + e2;
  rab = r * a / b;
  float ww2 = pp + td;
  float q2 = fmaxf(ww2, k);
  float f1 = expf(ww2 - q2);
  float f2 = expf(k - q2);
  naa = f1 * aa + f2 * v;
  nbb = f1 * bb + f2;
  npp = q2;
}

__global__ __launch_bounds__(BLOCK, 1) void k_rwkv(
    const int* __restrict__ ctx, const float* __restrict__ state,
    const float* __restrict__ emb, const float* __restrict__ ln0w,
    const float* __restrict__ ln0b, const float* __restrict__ ln1w,
    const float* __restrict__ ln1b, const float* __restrict__ amk,
    const float* __restrict__ amv, const float* __restrict__ amr,
    const float* __restrict__ tf, const float* __restrict__ td,
    const float* __restrict__ kw, const float* __restrict__ vw,
    const float* __restrict__ rw, const float* __restrict__ ow,
    const float* __restrict__ ln2w, const float* __restrict__ ln2b,
    const float* __restrict__ fmk, const float* __restrict__ fmr,
    const float* __restrict__ fkw, const float* __restrict__ fvw,
    const float* __restrict__ frw, const float* __restrict__ lnoutw,
    const float* __restrict__ lnoutb, const float* __restrict__ head,
    float* __restrict__ out, float* __restrict__ ws, unsigned* __restrict__ bar) {
  __shared__ __align__(16) float s_vx[N];   // layer input x
  __shared__ __align__(16) float s_sx[N];   // sx, persists AB(l+1)
  __shared__ __align__(16) float s_ex[16];  // k[4],v[4],r[4],rab[4]
  __shared__ __align__(16) float s_kk[16];
  __shared__ unsigned s_gen;

  const int tid = threadIdx.x;
  const int lane = tid & 63;
  const int wid = tid >> 6;
  const bool work = (wid > 0);
  const int blk = blockIdx.x;
  const int i0 = 2 * tid;
  const size_t nn = (size_t)N * N;

  if (tid == 0) s_gen = 0;
  __syncthreads();

  float* logits = out;
  float* st_out = out + VOCAB;
  float* r2buf = ws;
  float* sxacc = ws + SXACC_OFF;  // [2][4][N]
  float* facc = ws + FACC_OFF;    // [2][4][N]
  unsigned genc = 0;

  // XCD-team col ownership (4 blocks share a 16-col panel)
  const int xcd = blk & 7, sgrp = blk >> 3;
  const int jm = sgrp & 3, gg = sgrp >> 2;
  const int c0 = (((xcd + (gg << 3)) << 4) + (jm << 2));

  const int wl = (wid - 1) * 64 + lane;  // worker flat lane [0,448)
  // AB rows: 0-3 kw, 4-7 vw, 8-11 rw; waves1-7 own rI=wid-1; waves1-5 also rJ=wid+6
  const int rI = wid - 1, rJ = wid + 6;
  const bool hasJ = (wid >= 1 && wid <= 5);
  // C rows: 0-15 fkw, 16-19 frw; waves1-6 own 3; wave7 owns 2
  const int iA = (wid <= 6) ? 3 * (wid - 1) : 18;
  const int iB = iA + 1;
  const int iC = iA + 2;  // waves 1-6 only
  const bool hasC = (wid >= 1 && wid <= 6);
  // panel rows: workers 2/lane (0..895); wave0 2/lane (896..1023)
  const int rv0 = work ? ((wl + (blk << 2)) & (N - 1)) : ((896 + lane + (blk << 2)) & (N - 1));
  const int rv1 = work ? ((wl + 448 + (blk << 2)) & (N - 1)) : ((960 + lane + (blk << 2)) & (N - 1));

  float4 paI[4], paJ[4], powr0, powr1;
  float4 pkA[4], pkB[4], pkC[4], pf0[4], pf1[4];
  float kaa = 0.f, kbb = 0.f, kpp = 0.f, ktf = 0.f, ktd = 0.f;

  auto parow = [&](int r, int lc) -> const float* {
    int m = r >> 2;
    const float* base = (m == 0) ? kw : (m == 1) ? vw : rw;
    return base + (size_t)lc * nn + (size_t)(c0 + (r & 3)) * N;
  };
  auto pcrow = [&](int i, int lc) -> const float* {
    return (i < 16) ? fkw + (size_t)lc * F * N + (size_t)((blk << 4) + i) * N
                    : frw + (size_t)lc * nn + (size_t)((blk << 2) + (i - 16)) * N;
  };
  // workers: rows + own panel-ow. waves1-5: 10 loads; waves6-7: 6 loads.
  auto pfA_rows = [&](int lc) {
    const float* WI = parow(rI, lc);
#pragma unroll
    for (int k = 0; k < 4; ++k) paI[k] = ((const float4*)WI)[(k << 6) + lane];
    if (hasJ) {
      const float* WJ = parow(rJ, lc);
#pragma unroll
      for (int k = 0; k < 4; ++k) paJ[k] = ((const float4*)WJ)[(k << 6) + lane];
    }
    const float* owl = ow + (size_t)lc * nn;
    powr0 = *(const float4*)(owl + (size_t)rv0 * N + c0);
    powr1 = *(const float4*)(owl + (size_t)rv1 * N + c0);
  };
  // workers: C rows + own panel-fvw. waves1-6: 20 loads; wave7: 16 loads.
  auto pfC_rows = [&](int lc) {
    const float* WA = pcrow(iA, lc);
#pragma unroll
    for (int k = 0; k < 4; ++k) pkA[k] = ((const float4*)WA)[(k << 6) + lane];
    const float* WB = pcrow(iB, lc);
#pragma unroll
    for (int k = 0; k < 4; ++k) pkB[k] = ((const float4*)WB)[(k << 6) + lane];
    if (hasC) {
      const float* WC = pcrow(iC, lc);
#pragma unroll
      for (int k = 0; k < 4; ++k) pkC[k] = ((const float4*)WC)[(k << 6) + lane];
    }
    const float* fvb = fvw + (size_t)lc * N * F + (blk << 4);
#pragma unroll
    for (int i = 0; i < 4; ++i) pf0[i] = ((const float4*)(fvb + (size_t)rv0 * F))[i];
#pragma unroll
    for (int i = 0; i < 4; ++i) pf1[i] = ((const float4*)(fvb + (size_t)rv1 * F))[i];
  };
  // wave0: just its 2 ow panel rows (issued post-sweep)
  auto pfA_w0 = [&](int lc) {
    const float* owl = ow + (size_t)lc * nn;
    powr0 = *(const float4*)(owl + (size_t)rv0 * N + c0);
    powr1 = *(const float4*)(owl + (size_t)rv1 * N + c0);
  };
  // wave0: its 2 fvw panel rows
  auto pfC_w0 = [&](int lc) {
    const float* fvb = fvw + (size_t)lc * N * F + (blk << 4);
#pragma unroll
    for (int i = 0; i < 4; ++i) pf0[i] = ((const float4*)(fvb + (size_t)rv0 * F))[i];
#pragma unroll
    for (int i = 0; i < 4; ++i) pf1[i] = ((const float4*)(fvb + (size_t)rv1 * F))[i];
  };

  // ---- initial prefetch: layer 0 AB ----
  if (work) pfA_rows(0);
  else pfA_w0(0);

  for (int l = 0; l < NLAYERS; ++l) {
    const float* st_l = state + (size_t)l * 5 * N;
    float* sto = st_out + (size_t)l * 5 * N;
    const int p = l & 1;

    // ========= Stage AB: x, LN1, mix, k/v/r, WKV, ow col-panel =========
    {
      if (tid < 4) {
        int ii = c0 + tid;
        kaa = st_l[2 * N + ii];
        kbb = st_l[3 * N + ii];
        kpp = st_l[4 * N + ii];
        ktf = tf[l * N + ii];
        ktd = td[l * N + ii];
      }
      if (tid < 16) st_c(sxacc + (1 - p) * 4096 + blk * 16 + tid, 0.f);

      float2 xin;
      if (l == 0) {
        int t1 = ctx[1], t0c = ctx[0];
        float2 e1 = ((const float2*)(emb + (size_t)t1 * N))[tid];
        float2 e0 = ((const float2*)(emb + (size_t)t0c * N))[tid];
        xin.x = (e1.x * 4.f + e0.x) * 0.2f;
        xin.y = (e1.y * 4.f + e0.y) * 0.2f;
      } else {
        float2 r22 = ld_c2(r2buf + i0);
        const float* fb = facc + (1 - p) * 4096;
        float fax = 0.f, fay = 0.f;
#pragma unroll
        for (int c = 0; c < 4; ++c) {
          float2 t2 = ld_c2(fb + c * N + i0);
          fax += t2.x;
          fay += t2.y;
        }
        xin.x = s_sx[i0] + r22.x * fax;
        xin.y = s_sx[i0 + 1] + r22.y * fay;
      }
      ((float2*)s_vx)[tid] = xin;
      lbar();
      float4 xq[4];
      if (work) {
#pragma unroll
        for (int k = 0; k < 4; ++k) xq[k] = ((const float4*)s_vx)[(k << 6) + lane];
      }
      if (l == 0) {
        if (work) ln16(xq, ln0w, ln0b, lane);
        lbar();  // everyone done reading raw x
        if (wid == 1) {
#pragma unroll
          for (int k = 0; k < 4; ++k) ((float4*)s_vx)[(k << 6) + lane] = xq[k];
        }
        // visible to stage C via later lgkm drains
      }
      if (work) {
        float4 xl[4];
#pragma unroll
        for (int k = 0; k < 4; ++k) xl[k] = xq[k];
        ln16(xl, ln1w + l * N, ln1b + l * N, lane);
        if (blk == 4 && wid == 1) {
#pragma unroll
          for (int k = 0; k < 4; ++k) ((float4*)(sto + N))[(k << 6) + lane] = xl[k];
        }
        int mI = rI >> 2;
        float dI = 0.f, dJ = 0.f;
#pragma unroll
        for (int k = 0; k < 4; ++k) {
          float4 s1 = ((const float4*)(st_l + N))[(k << 6) + lane];
          float4 mk = mix4(xl[k], s1, ((const float4*)(amk + l * N))[(k << 6) + lane]);
          float4 mv = mix4(xl[k], s1, ((const float4*)(amv + l * N))[(k << 6) + lane]);
          float4 mr = mix4(xl[k], s1, ((const float4*)(amr + l * N))[(k << 6) + lane]);
          float4 mmI = (mI == 0) ? mk : ((mI == 1) ? mv : mr);
          dI += dot4(paI[k], mmI);
          if (hasJ) {
            int mJ = rJ >> 2;
            float4 mmJ = (mJ == 1) ? mv : mr;
            dJ += dot4(paJ[k], mmJ);
          }
        }
        dI = wred(dI);
        if (lane == 0) s_ex[rI] = (rI >= 8) ? sigmoidf(dI) : dI;
        if (hasJ) {
          dJ = wred(dJ);
          if (lane == 0) s_ex[rJ] = (rJ >= 8) ? sigmoidf(dJ) : dJ;
        }
      }
      lbar();
      if (tid < 4) {
        float rab, naa, nbb, npp;
        wkv1(s_ex[tid], s_ex[4 + tid], s_ex[8 + tid], kaa, kbb, kpp, ktf, ktd,
             rab, naa, nbb, npp);
        int ii = c0 + tid;
        sto[2 * N + ii] = naa;
        sto[3 * N + ii] = nbb;
        sto[4 * N + ii] = npp;
        s_ex[12 + tid] = rab;
      }
      lbar();
      {
        float4 rab4 = *((const float4*)(s_ex + 12));
        float* sxa = sxacc + p * 4096 + (blk & 3) * N;
        unsafeAtomicAdd(sxa + rv0, dot4(powr0, rab4));
        unsafeAtomicAdd(sxa + rv1, dot4(powr1, rab4));
      }
    }
    // ---- workers: pre-issue C weights; counted drain (atomics pinned older) ----
    __builtin_amdgcn_sched_barrier(0);
    if (work) {
      pfC_rows(l);
      __builtin_amdgcn_sched_barrier(0);
      if (wid <= 6) DRAIN(20);
      else DRAIN(16);
    } else {
      DRAIN(0);
    }
    arrive_flag(bar, ++genc, blk, tid);
    if (!work) {
      sweep_signal(bar, genc, lane, &s_gen);
      pfC_w0(l);  // wave0's 2 fvw panel rows, post-sweep (consumed at stage end)
    } else {
      lds_wait(&s_gen, genc);
    }

    // ========= Stage C: sx, LN2, mix, ffn_k, ffn_r, fvw col-panel =========
    {
      if (tid < 16) st_c(facc + (1 - p) * 4096 + blk * 16 + tid, 0.f);
      const float* sb = sxacc + p * 4096;
      float fax = 0.f, fay = 0.f;
#pragma unroll
      for (int c = 0; c < 4; ++c) {
        float2 t2 = ld_c2(sb + c * N + i0);
        fax += t2.x;
        fay += t2.y;
      }
      float2 sx2;
      sx2.x = s_vx[i0] + fax;
      sx2.y = s_vx[i0 + 1] + fay;
      ((float2*)s_sx)[tid] = sx2;
      lbar();
      if (work) {
        float4 x2q[4];
#pragma unroll
        for (int k = 0; k < 4; ++k) x2q[k] = ((const float4*)s_sx)[(k << 6) + lane];
        ln16(x2q, ln2w + l * N, ln2b + l * N, lane);
        if (blk == 5 && wid == 1) {
#pragma unroll
          for (int k = 0; k < 4; ++k) ((float4*)sto)[(k << 6) + lane] = x2q[k];
        }
        float dA = 0.f, dB = 0.f, dC = 0.f;
#pragma unroll
        for (int k = 0; k < 4; ++k) {
          float4 s0 = ((const float4*)st_l)[(k << 6) + lane];
          float4 mk = mix4(x2q[k], s0, ((const float4*)(fmk + l * N))[(k << 6) + lane]);
          float4 mr = mix4(x2q[k], s0, ((const float4*)(fmr + l * N))[(k << 6) + lane]);
          dA += dot4(pkA[k], (iA < 16) ? mk : mr);
          dB += dot4(pkB[k], (iB < 16) ? mk : mr);
          if (hasC) dC += dot4(pkC[k], (iC < 16) ? mk : mr);
        }
        dA = wred(dA);
        dB = wred(dB);
        if (hasC) dC = wred(dC);
        if (lane == 0) {
          if (iA < 16) { float t = fmaxf(dA, 0.f); s_kk[iA] = t * t; }
          else st_c(r2buf + (blk << 2) + (iA - 16), sigmoidf(dA));
          if (iB < 16) { float t = fmaxf(dB, 0.f); s_kk[iB] = t * t; }
          else st_c(r2buf + (blk << 2) + (iB - 16), sigmoidf(dB));
          if (hasC) {
            if (iC < 16) { float t = fmaxf(dC, 0.f); s_kk[iC] = t * t; }
            else st_c(r2buf + (blk << 2) + (iC - 16), sigmoidf(dC));
          }
        }
      }
      lbar();
      {
        float4 K0 = ((const float4*)s_kk)[0];
        float4 K1 = ((const float4*)s_kk)[1];
        float4 K2 = ((const float4*)s_kk)[2];
        float4 K3 = ((const float4*)s_kk)[3];
        float* fc = facc + p * 4096 + (blk & 3) * N;
        unsafeAtomicAdd(fc + rv0, dot4(pf0[0], K0) + dot4(pf0[1], K1) +
                                      dot4(pf0[2], K2) + dot4(pf0[3], K3));
        unsafeAtomicAdd(fc + rv1, dot4(pf1[0], K0) + dot4(pf1[1], K1) +
                                      dot4(pf1[2], K2) + dot4(pf1[3], K3));
      }
    }
    // ---- workers: pre-issue AB(l+1) weights; counted drain ----
    const bool ldav = (l + 1 < NLAYERS);
    __builtin_amdgcn_sched_barrier(0);
    if (work && ldav) {
      pfA_rows(l + 1);
      __builtin_amdgcn_sched_barrier(0);
      if (wid <= 5) DRAIN(10);
      else DRAIN(6);
    } else {
      DRAIN(0);
    }
    arrive_flag(bar, ++genc, blk, tid);
    if (!work) {
      sweep_signal(bar, genc, lane, &s_gen);
      if (ldav) pfA_w0(l + 1);  // wave0's 2 ow panel rows, post-sweep
    } else {
      lds_wait(&s_gen, genc);
    }
  }

  // ================= head: logits = head @ LN(x_final) =================
  {
    float2 r22 = ld_c2(r2buf + i0);
    const float* fb = facc + ((NLAYERS - 1) & 1) * 4096;
    float fax = 0.f, fay = 0.f;
#pragma unroll
    for (int c = 0; c < 4; ++c) {
      float2 t2 = ld_c2(fb + c * N + i0);
      fax += t2.x;
      fay += t2.y;
    }
    float2 xf2;
    xf2.x = s_sx[i0] + r22.x * fax;
    xf2.y = s_sx[i0 + 1] + r22.y * fay;
    ((float2*)s_vx)[tid] = xf2;
    lbar();
    float4 xf[4];
#pragma unroll
    for (int k = 0; k < 4; ++k) xf[k] = ((const float4*)s_vx)[(k << 6) + lane];
    ln16(xf, lnoutw, lnoutb, lane);
    int gw = (blk << 3) + wid;
    for (int base = gw * 4; base < VOCAB; base += GRID * 8 * 4) {
      float4 h[4][4];
#pragma unroll
      for (int rr = 0; rr < 4; ++rr) {
        int row = base + rr;
        if (row < VOCAB) {
          const float4* hp = (const float4*)(head + (size_t)row * N);
#pragma unroll
          for (int k = 0; k < 4; ++k) h[rr][k] = hp[(k << 6) + lane];
        }
      }
#pragma unroll
      for (int rr = 0; rr < 4; ++rr) {
        int row = base + rr;
        if (row < VOCAB) {
          float d = 0.f;
#pragma unroll
          for (int k = 0; k < 4; ++k) d += dot4(h[rr][k], xf[k]);
          d = wred(d);
          if (lane == 0) logits[row] = d;
        }
      }
    }
  }
}

extern "C" void kernel_launch(void* const* d_in, const int* in_sizes, int n_in,
                              void* d_out, int out_size, void* d_ws, size_t ws_size,
                              hipStream_t stream) {
  const int* ctx = (const int*)d_in[0];
  const float* state = (const float*)d_in[1];
  const float* emb = (const float*)d_in[2];
  const float* ln0w = (const float*)d_in[3];
  const float* ln0b = (const float*)d_in[4];
  const float* ln1w = (const float*)d_in[5];
  const float* ln1b = (const float*)d_in[6];
  const float* amk = (const float*)d_in[7];
  const float* amv = (const float*)d_in[8];
  const float* amr = (const float*)d_in[9];
  const float* tf = (const float*)d_in[10];
  const float* td = (const float*)d_in[11];
  const float* kw = (const float*)d_in[12];
  const float* vw = (const float*)d_in[13];
  const float* rw = (const float*)d_in[14];
  const float* ow = (const float*)d_in[15];
  const float* ln2w = (const float*)d_in[16];
  const float* ln2b = (const float*)d_in[17];
  const float* fmk = (const float*)d_in[18];
  const float* fmr = (const float*)d_in[19];
  const float* fkw = (const float*)d_in[20];
  const float* fvw = (const float*)d_in[21];
  const float* frw = (const float*)d_in[22];
  const float* lnoutw = (const float*)d_in[23];
  const float* lnoutb = (const float*)d_in[24];
  const float* head = (const float*)d_in[25];
  float* out = (float*)d_out;
  float* ws = (float*)d_ws;
  unsigned* bar = (unsigned*)((char*)d_ws + BAR_OFF_BYTES);

  hipMemsetAsync(d_ws, 0, WS_CLEAR_BYTES, stream);

  void* args[] = {&ctx, &state, &emb, &ln0w, &ln0b, &ln1w, &ln1b,
                  &amk, &amv, &amr, &tf, &td, &kw, &vw, &rw, &ow,
                  &ln2w, &ln2b, &fmk, &fmr, &fkw, &fvw, &frw,
                  &lnoutw, &lnoutb, &head, &out, &ws, &bar};
  hipLaunchCooperativeKernel((const void*)k_rwkv, dim3(GRID), dim3(BLOCK),
                             args, 0, stream);
}

// Round 17
// 677.224 us; speedup vs baseline: 1.8815x; 1.4609x over previous
//
#include <hip/hip_runtime.h>
#include <math.h>

#define N 1024
#define F 4096
#define NLAYERS 24
#define VOCAB 50277
#define GRID 256
#define BLOCK 512   // wave0 = sweeper+WKV+panel (no row dots), waves 1-7 = row workers

// ws floats: r2buf[N]@0; sxacc[2][4][N]@N; facc[2][4][N]@N+8192
#define SXACC_OFF N
#define FACC_OFF (N + 8192)
#define BAR_OFF_BYTES 69632
#define LINE 16
#define BAR_DWORDS (256 * LINE)
#define WS_CLEAR_BYTES (BAR_OFF_BYTES + BAR_DWORDS * 4)

__device__ __forceinline__ float dot4(float4 a, float4 b) {
  return fmaf(a.x, b.x, fmaf(a.y, b.y, fmaf(a.z, b.z, a.w * b.w)));
}
__device__ __forceinline__ float wred(float v) {
#pragma unroll
  for (int o = 32; o > 0; o >>= 1) v += __shfl_down(v, o, 64);
  return v;
}
__device__ __forceinline__ float bfly(float v) {
#pragma unroll
  for (int o = 1; o < 64; o <<= 1) v += __shfl_xor(v, o, 64);
  return v;
}
__device__ __forceinline__ float sigmoidf(float x) { return 1.f / (1.f + expf(-x)); }

__device__ __forceinline__ float2 ld_c2(const float* p) {
  unsigned long long u = __hip_atomic_load((const unsigned long long*)p,
                                           __ATOMIC_RELAXED, __HIP_MEMORY_SCOPE_AGENT);
  float2 f;
  f.x = __uint_as_float((unsigned)u);
  f.y = __uint_as_float((unsigned)(u >> 32));
  return f;
}
__device__ __forceinline__ void st_c(float* p, float v) {
  __hip_atomic_store(p, v, __ATOMIC_RELAXED, __HIP_MEMORY_SCOPE_AGENT);
}
__device__ __forceinline__ unsigned ld_cu(const unsigned* p) {
  return __hip_atomic_load(p, __ATOMIC_RELAXED, __HIP_MEMORY_SCOPE_AGENT);
}
__device__ __forceinline__ void st_cu(unsigned* p, unsigned v) {
  __hip_atomic_store(p, v, __ATOMIC_RELAXED, __HIP_MEMORY_SCOPE_AGENT);
}

__device__ __forceinline__ void lbar() {
  asm volatile("s_waitcnt lgkmcnt(0)" ::: "memory");
  __builtin_amdgcn_s_barrier();
}

// arrive: full drain (R12 semantics), block barrier, flag store
__device__ __forceinline__ void gbar_arrive(unsigned* arr, unsigned gen, int blk,
                                            int tid) {
  asm volatile("s_waitcnt vmcnt(0) lgkmcnt(0)" ::: "memory");
  __builtin_amdgcn_s_barrier();
  if (tid == 0) st_cu(arr + blk * LINE, gen);
}
// wave0 (vmem-clean): sweep all 256 flags, signal via LDS
__device__ __forceinline__ void sweep_signal(const unsigned* arr, unsigned gen,
                                             int lane, unsigned* s_gen) {
  for (;;) {
    bool ok = true;
#pragma unroll
    for (int i = 0; i < 4; ++i)
      ok &= (ld_cu(arr + (lane * 4 + i) * LINE) >= gen);
    if (__all(ok)) break;
    __builtin_amdgcn_s_sleep(1);
  }
  __hip_atomic_store(s_gen, gen, __ATOMIC_RELEASE, __HIP_MEMORY_SCOPE_WORKGROUP);
}
__device__ __forceinline__ void lds_wait(const unsigned* s_gen, unsigned gen) {
  while (__hip_atomic_load(s_gen, __ATOMIC_ACQUIRE, __HIP_MEMORY_SCOPE_WORKGROUP) < gen)
    __builtin_amdgcn_s_sleep(1);
  asm volatile("" ::: "memory");
}

// redundant-per-wave LayerNorm of 16 lane-columns in q[4]
__device__ __forceinline__ void ln16(float4* q, const float* __restrict__ w,
                                     const float* __restrict__ b, int lane) {
  float s = 0.f, sq = 0.f;
#pragma unroll
  for (int k = 0; k < 4; ++k) {
    s += q[k].x + q[k].y + q[k].z + q[k].w;
    sq += dot4(q[k], q[k]);
  }
  s = bfly(s);
  sq = bfly(sq);
  float mu = s * (1.f / N);
  float rstd = rsqrtf(sq * (1.f / N) - mu * mu + 1e-5f);
#pragma unroll
  for (int k = 0; k < 4; ++k) {
    float4 w4 = ((const float4*)w)[(k << 6) + lane];
    float4 b4 = ((const float4*)b)[(k << 6) + lane];
    q[k].x = (q[k].x - mu) * rstd * w4.x + b4.x;
    q[k].y = (q[k].y - mu) * rstd * w4.y + b4.y;
    q[k].z = (q[k].z - mu) * rstd * w4.z + b4.z;
    q[k].w = (q[k].w - mu) * rstd * w4.w + b4.w;
  }
}

__device__ __forceinline__ float4 mix4(float4 a, float4 s, float4 m) {
  float4 r;
  r.x = a.x * m.x + s.x * (1.f - m.x);
  r.y = a.y * m.y + s.y * (1.f - m.y);
  r.z = a.z * m.z + s.z * (1.f - m.z);
  r.w = a.w * m.w + s.w * (1.f - m.w);
  return r;
}

__device__ __forceinline__ void wkv1(float k, float v, float r, float aa, float bb,
                                     float pp, float tf, float td, float& rab,
                                     float& naa, float& nbb, float& npp) {
  float ww = tf + k;
  float q = fmaxf(pp, ww);
  float e1 = expf(pp - q);
  float e2 = expf(ww - q);
  float a = e1 * aa + e2 * v;
  float b = e1 * bb + e2;
  rab = r * a / b;
  float ww2 = pp + td;
  float q2 = fmaxf(ww2, k);
  float f1 = expf(ww2 - q2);
  float f2 = expf(k - q2);
  naa = f1 * aa + f2 * v;
  nbb = f1 * bb + f2;
  npp = q2;
}

__global__ __launch_bounds__(BLOCK, 1) void k_rwkv(
    const int* __restrict__ ctx, const float* __restrict__ state,
    const float* __restrict__ emb, const float* __restrict__ ln0w,
    const float* __restrict__ ln0b, const float* __restrict__ ln1w,
    const float* __restrict__ ln1b, const float* __restrict__ amk,
    const float* __restrict__ amv, const float* __restrict__ amr,
    const float* __restrict__ tf, const float* __restrict__ td,
    const float* __restrict__ kw, const float* __restrict__ vw,
    const float* __restrict__ rw, const float* __restrict__ ow,
    const float* __restrict__ ln2w, const float* __restrict__ ln2b,
    const float* __restrict__ fmk, const float* __restrict__ fmr,
    const float* __restrict__ fkw, const float* __restrict__ fvw,
    const float* __restrict__ frw, const float* __restrict__ lnoutw,
    const float* __restrict__ lnoutb, const float* __restrict__ head,
    float* __restrict__ out, float* __restrict__ ws, unsigned* __restrict__ bar) {
  __shared__ __align__(16) float s_vx[N];   // layer input x
  __shared__ __align__(16) float s_sx[N];   // sx, persists to next AB
  __shared__ __align__(16) float s_kk[16];
  __shared__ __align__(16) float s_ex[16];  // k[4],v[4],r[4],rab[4]
  __shared__ unsigned s_gen;

  const int tid = threadIdx.x;
  const int lane = tid & 63;
  const int wid = tid >> 6;
  const bool work = (wid > 0);
  const int blk = blockIdx.x;
  const int i0 = 2 * tid;
  const size_t nn = (size_t)N * N;

  if (tid == 0) s_gen = 0;
  __syncthreads();

  float* logits = out;
  float* st_out = out + VOCAB;
  float* r2buf = ws;
  float* sxacc = ws + SXACC_OFF;  // [2][4][N]
  float* facc = ws + FACC_OFF;    // [2][4][N]
  unsigned genc = 0;

  // XCD-team row/col ownership: 4 blocks with same (blk%8) share a 16-col panel
  const int xcd = blk & 7, sgrp = blk >> 3;
  const int jm = sgrp & 3, gg = sgrp >> 2;
  const int tt = xcd + (gg << 3);
  const int c0 = (tt << 4) + (jm << 2);

  // ---- AB row assignment (wave0 offloaded) ----
  // dI: wid1-3 -> kw row (c0+wid), s_ex[wid], mix mk
  //     wid4-7 -> vw row (c0+wid-4), s_ex[4+wid-4], mix mv
  // dJ: wid1-3 -> rw row (c0+wid), s_ex[8+wid], mix mr
  //     wid4   -> kw row (c0+0),   s_ex[0],     mix mk
  //     wid5   -> rw row (c0+0),   s_ex[8],     mix mr
  const bool lo = (wid >= 1 && wid <= 3);
  const int rowI = lo ? (c0 + wid) : (c0 + (wid & 3));           // kw or vw row
  const int exI = lo ? wid : (4 + (wid & 3));
  const bool hasJ = (wid >= 1 && wid <= 5);
  const int rowJ = lo ? (c0 + wid) : c0;                          // rw/kw/rw row 0
  const int exJ = lo ? (8 + wid) : ((wid == 4) ? 0 : 8);
  const int mixJ = (wid == 4) ? 0 : 2;                            // 0=mk 2=mr
  const bool needK = lo || (wid == 4);
  const bool needV = (wid >= 4);
  const bool needR = lo || (wid == 5);
  // ---- C row assignment ----
  // pk0 -> fkw row (blk*16+wid) -> s_kk[wid];  pk1 -> +8 -> s_kk[8+wid]
  // third: wid1 -> fkw row +0 -> s_kk[0]; wid2 -> fkw row +8.. wait row (blk*16+8)
  //        is pk1 of wid0 in R12; here wid2's third = fkw row (blk*16+8)? No:
  //        pk1 rows are 9..15 for wid1..7; third rows fill 0 and 8.
  const int gk0 = (blk << 4) + wid, gk1 = gk0 + 8;
  const bool c3k = (wid == 1 || wid == 2);            // third row is fkw
  const int gk2 = (blk << 4) + ((wid == 1) ? 0 : 8);  // fkw row 0 or 8
  const bool c3r = (wid >= 4);                        // third row is frw
  const int rR = (blk << 2) + (wid & 3);              // frw row for wid4-7
  // panel rows: all 512 threads, 2 each (R12 layout)
  const int rv0 = (tid + (blk << 2)) & (N - 1);
  const int rv1 = (rv0 + 512) & (N - 1);

  float4 pa0[4], pa1[4], pow0, pow1, pk0[4], pk1[4], pcr[4], pf0[4], pf1[4];

  auto pfA_rows = [&](int lc) {  // workers: 10 loads (wid1-5) / 6 (wid6-7)
    const float* W0 = (lo ? kw : vw) + (size_t)lc * nn + (size_t)rowI * N;
#pragma unroll
    for (int k = 0; k < 4; ++k) pa0[k] = ((const float4*)W0)[(k << 6) + lane];
    if (hasJ) {
      const float* W1 = (lo ? rw : ((wid == 4) ? kw : rw)) + (size_t)lc * nn +
                        (size_t)rowJ * N;
#pragma unroll
      for (int k = 0; k < 4; ++k) pa1[k] = ((const float4*)W1)[(k << 6) + lane];
    }
    const float* owl = ow + (size_t)lc * nn;
    pow0 = *(const float4*)(owl + (size_t)rv0 * N + c0);
    pow1 = *(const float4*)(owl + (size_t)rv1 * N + c0);
  };
  auto pfA_w0 = [&](int lc) {  // wave0: 2 loads, post-sweep
    const float* owl = ow + (size_t)lc * nn;
    pow0 = *(const float4*)(owl + (size_t)rv0 * N + c0);
    pow1 = *(const float4*)(owl + (size_t)rv1 * N + c0);
  };
  auto pfC_rows = [&](int lc) {  // workers: 20 (wid1,2,4-7) / 16 (wid3)
    const float* fkw_l = fkw + (size_t)lc * F * N;
#pragma unroll
    for (int k = 0; k < 4; ++k)
      pk0[k] = ((const float4*)(fkw_l + (size_t)gk0 * N))[(k << 6) + lane];
#pragma unroll
    for (int k = 0; k < 4; ++k)
      pk1[k] = ((const float4*)(fkw_l + (size_t)gk1 * N))[(k << 6) + lane];
    if (c3k) {
#pragma unroll
      for (int k = 0; k < 4; ++k)
        pcr[k] = ((const float4*)(fkw_l + (size_t)gk2 * N))[(k << 6) + lane];
    } else if (c3r) {
      const float* WR = frw + (size_t)lc * nn + (size_t)rR * N;
#pragma unroll
      for (int k = 0; k < 4; ++k) pcr[k] = ((const float4*)WR)[(k << 6) + lane];
    }
    const float* fvb = fvw + (size_t)lc * N * F + (blk << 4);
#pragma unroll
    for (int i = 0; i < 4; ++i) pf0[i] = ((const float4*)(fvb + (size_t)rv0 * F))[i];
#pragma unroll
    for (int i = 0; i < 4; ++i) pf1[i] = ((const float4*)(fvb + (size_t)rv1 * F))[i];
  };
  auto pfC_w0 = [&](int lc) {  // wave0: 8 loads, post-sweep
    const float* fvb = fvw + (size_t)lc * N * F + (blk << 4);
#pragma unroll
    for (int i = 0; i < 4; ++i) pf0[i] = ((const float4*)(fvb + (size_t)rv0 * F))[i];
#pragma unroll
    for (int i = 0; i < 4; ++i) pf1[i] = ((const float4*)(fvb + (size_t)rv1 * F))[i];
  };

  // ---- initial prefetch: layer 0 AB ----
  if (work) pfA_rows(0);
  else pfA_w0(0);

  for (int l = 0; l < NLAYERS; ++l) {
    const float* st_l = state + (size_t)l * 5 * N;
    float* sto = st_out + (size_t)l * 5 * N;
    const int p = l & 1;

    // ========= Stage AB =========
    {
      float kaa = 0.f, kbb = 0.f, kpp = 0.f, ktf = 0.f, ktd = 0.f;
      if (tid < 4) {
        int ii = c0 + tid;
        kaa = st_l[2 * N + ii];
        kbb = st_l[3 * N + ii];
        kpp = st_l[4 * N + ii];
        ktf = tf[l * N + ii];
        ktd = td[l * N + ii];
      }
      if (tid < 16) st_c(sxacc + (1 - p) * 4096 + blk * 16 + tid, 0.f);

      float2 xin;
      if (l == 0) {
        int t1 = ctx[1], t0c = ctx[0];
        float2 e1 = ((const float2*)(emb + (size_t)t1 * N))[tid];
        float2 e0 = ((const float2*)(emb + (size_t)t0c * N))[tid];
        xin.x = (e1.x * 4.f + e0.x) * 0.2f;
        xin.y = (e1.y * 4.f + e0.y) * 0.2f;
      } else {
        float2 r22 = ld_c2(r2buf + i0);
        const float* fb = facc + (1 - p) * 4096;
        float fax = 0.f, fay = 0.f;
#pragma unroll
        for (int c = 0; c < 4; ++c) {
          float2 t2 = ld_c2(fb + c * N + i0);
          fax += t2.x;
          fay += t2.y;
        }
        xin.x = s_sx[i0] + r22.x * fax;
        xin.y = s_sx[i0 + 1] + r22.y * fay;
      }
      ((float2*)s_vx)[tid] = xin;
      lbar();
      float4 xq[4];
      if (work) {
#pragma unroll
        for (int k = 0; k < 4; ++k) xq[k] = ((const float4*)s_vx)[(k << 6) + lane];
      }
      if (l == 0) {
        if (work) ln16(xq, ln0w, ln0b, lane);
        lbar();
        if (wid == 1) {
#pragma unroll
          for (int k = 0; k < 4; ++k) ((float4*)s_vx)[(k << 6) + lane] = xq[k];
        }
      }
      if (work) {
        float4 xl[4];
#pragma unroll
        for (int k = 0; k < 4; ++k) xl[k] = xq[k];
        ln16(xl, ln1w + l * N, ln1b + l * N, lane);
        if (blk == 4 && wid == 1) {
#pragma unroll
          for (int k = 0; k < 4; ++k) ((float4*)(sto + N))[(k << 6) + lane] = xl[k];
        }
        float dI = 0.f, dJ = 0.f;
#pragma unroll
        for (int k = 0; k < 4; ++k) {
          float4 s1 = ((const float4*)(st_l + N))[(k << 6) + lane];
          float4 mk, mv, mr;
          if (needK) mk = mix4(xl[k], s1, ((const float4*)(amk + l * N))[(k << 6) + lane]);
          if (needV) mv = mix4(xl[k], s1, ((const float4*)(amv + l * N))[(k << 6) + lane]);
          if (needR) mr = mix4(xl[k], s1, ((const float4*)(amr + l * N))[(k << 6) + lane]);
          float4 mmI = lo ? mk : mv;
          dI += dot4(pa0[k], mmI);
          if (hasJ) {
            float4 mmJ = (mixJ == 0) ? mk : mr;
            dJ += dot4(pa1[k], mmJ);
          }
        }
        dI = wred(dI);
        if (lane == 0) s_ex[exI] = dI;  // exI is never an r-row
        if (hasJ) {
          dJ = wred(dJ);
          if (lane == 0) s_ex[exJ] = (exJ >= 8) ? sigmoidf(dJ) : dJ;
        }
      }
      lbar();
      if (tid < 4) {
        float rab, naa, nbb, npp;
        wkv1(s_ex[tid], s_ex[4 + tid], s_ex[8 + tid], kaa, kbb, kpp, ktf, ktd,
             rab, naa, nbb, npp);
        int ii = c0 + tid;
        sto[2 * N + ii] = naa;
        sto[3 * N + ii] = nbb;
        sto[4 * N + ii] = npp;
        s_ex[12 + tid] = rab;
      }
      lbar();
      float4 rab4 = *((const float4*)(s_ex + 12));
      float* sxa = sxacc + p * 4096 + (blk & 3) * N;
      unsafeAtomicAdd(sxa + rv0, dot4(pow0, rab4));
      unsafeAtomicAdd(sxa + rv1, dot4(pow1, rab4));
    }
    gbar_arrive(bar, ++genc, blk, tid);
    if (wid == 0) {
      sweep_signal(bar, genc, lane, &s_gen);
      pfC_w0(l);   // wave0's 2 fvw panel rows, post-sweep
    } else {
      pfC_rows(l);
      lds_wait(&s_gen, genc);
    }

    // ========= Stage C =========
    {
      if (tid < 16) st_c(facc + (1 - p) * 4096 + blk * 16 + tid, 0.f);
      const float* sb = sxacc + p * 4096;
      float fax = 0.f, fay = 0.f;
#pragma unroll
      for (int c = 0; c < 4; ++c) {
        float2 t2 = ld_c2(sb + c * N + i0);
        fax += t2.x;
        fay += t2.y;
      }
      float2 sx2;
      sx2.x = s_vx[i0] + fax;
      sx2.y = s_vx[i0 + 1] + fay;
      ((float2*)s_sx)[tid] = sx2;
      lbar();
      if (work) {
        float4 x2q[4];
#pragma unroll
        for (int k = 0; k < 4; ++k) x2q[k] = ((const float4*)s_sx)[(k << 6) + lane];
        ln16(x2q, ln2w + l * N, ln2b + l * N, lane);
        if (blk == 5 && wid == 1) {
#pragma unroll
          for (int k = 0; k < 4; ++k) ((float4*)sto)[(k << 6) + lane] = x2q[k];
        }
        float d0 = 0.f, d1 = 0.f, d2 = 0.f;
#pragma unroll
        for (int k = 0; k < 4; ++k) {
          float4 s0 = ((const float4*)st_l)[(k << 6) + lane];
          float4 mk = mix4(x2q[k], s0, ((const float4*)(fmk + l * N))[(k << 6) + lane]);
          d0 += dot4(pk0[k], mk);
          d1 += dot4(pk1[k], mk);
          if (c3k) {
            d2 += dot4(pcr[k], mk);
          } else if (c3r) {
            float4 mr = mix4(x2q[k], s0, ((const float4*)(fmr + l * N))[(k << 6) + lane]);
            d2 += dot4(pcr[k], mr);
          }
        }
        d0 = wred(d0);
        d1 = wred(d1);
        if (c3k || c3r) d2 = wred(d2);
        if (lane == 0) {
          float t0 = fmaxf(d0, 0.f);
          s_kk[wid] = t0 * t0;
          float t1 = fmaxf(d1, 0.f);
          s_kk[8 + wid] = t1 * t1;
          if (c3k) {
            float t2v = fmaxf(d2, 0.f);
            s_kk[(wid == 1) ? 0 : 8] = t2v * t2v;
          } else if (c3r) {
            st_c(r2buf + rR, sigmoidf(d2));
          }
        }
      }
      lbar();
      float4 K0 = ((const float4*)s_kk)[0];
      float4 K1 = ((const float4*)s_kk)[1];
      float4 K2 = ((const float4*)s_kk)[2];
      float4 K3 = ((const float4*)s_kk)[3];
      float* fc = facc + p * 4096 + (blk & 3) * N;
      unsafeAtomicAdd(fc + rv0, dot4(pf0[0], K0) + dot4(pf0[1], K1) +
                                    dot4(pf0[2], K2) + dot4(pf0[3], K3));
      unsafeAtomicAdd(fc + rv1, dot4(pf1[0], K0) + dot4(pf1[1], K1) +
                                    dot4(pf1[2], K2) + dot4(pf1[3], K3));
    }
    gbar_arrive(bar, ++genc, blk, tid);
    {
      const bool ldav = (l + 1 < NLAYERS);
      if (wid == 0) {
        sweep_signal(bar, genc, lane, &s_gen);
        if (ldav) pfA_w0(l + 1);
      } else {
        if (ldav) pfA_rows(l + 1);
        lds_wait(&s_gen, genc);
      }
    }
  }

  // ================= head: logits = head @ LN(x_final) =================
  {
    float2 r22 = ld_c2(r2buf + i0);
    const float* fb = facc + ((NLAYERS - 1) & 1) * 4096;
    float fax = 0.f, fay = 0.f;
#pragma unroll
    for (int c = 0; c < 4; ++c) {
      float2 t2 = ld_c2(fb + c * N + i0);
      fax += t2.x;
      fay += t2.y;
    }
    float2 xf2;
    xf2.x = s_sx[i0] + r22.x * fax;
    xf2.y = s_sx[i0 + 1] + r22.y * fay;
    ((float2*)s_vx)[tid] = xf2;
    lbar();
    float4 xf[4];
#pragma unroll
    for (int k = 0; k < 4; ++k) xf[k] = ((const float4*)s_vx)[(k << 6) + lane];
    ln16(xf, lnoutw, lnoutb, lane);
    int gw = (blk << 3) + wid;
    for (int base = gw * 4; base < VOCAB; base += GRID * 8 * 4) {
      float4 h[4][4];
#pragma unroll
      for (int rr = 0; rr < 4; ++rr) {
        int row = base + rr;
        if (row < VOCAB) {
          const float4* hp = (const float4*)(head + (size_t)row * N);
#pragma unroll
          for (int k = 0; k < 4; ++k) h[rr][k] = hp[(k << 6) + lane];
        }
      }
#pragma unroll
      for (int rr = 0; rr < 4; ++rr) {
        int row = base + rr;
        if (row < VOCAB) {
          float d = 0.f;
#pragma unroll
          for (int k = 0; k < 4; ++k) d += dot4(h[rr][k], xf[k]);
          d = wred(d);
          if (lane == 0) logits[row] = d;
        }
      }
    }
  }
}

extern "C" void kernel_launch(void* const* d_in, const int* in_sizes, int n_in,
                              void* d_out, int out_size, void* d_ws, size_t ws_size,
                              hipStream_t stream) {
  const int* ctx = (const int*)d_in[0];
  const float* state = (const float*)d_in[1];
  const float* emb = (const float*)d_in[2];
  const float* ln0w = (const float*)d_in[3];
  const float* ln0b = (const float*)d_in[4];
  const float* ln1w = (const float*)d_in[5];
  const float* ln1b = (const float*)d_in[6];
  const float* amk = (const float*)d_in[7];
  const float* amv = (const float*)d_in[8];
  const float* amr = (const float*)d_in[9];
  const float* tf = (const float*)d_in[10];
  const float* td = (const float*)d_in[11];
  const float* kw = (const float*)d_in[12];
  const float* vw = (const float*)d_in[13];
  const float* rw = (const float*)d_in[14];
  const float* ow = (const float*)d_in[15];
  const float* ln2w = (const float*)d_in[16];
  const float* ln2b = (const float*)d_in[17];
  const float* fmk = (const float*)d_in[18];
  const float* fmr = (const float*)d_in[19];
  const float* fkw = (const float*)d_in[20];
  const float* fvw = (const float*)d_in[21];
  const float* frw = (const float*)d_in[22];
  const float* lnoutw = (const float*)d_in[23];
  const float* lnoutb = (const float*)d_in[24];
  const float* head = (const float*)d_in[25];
  float* out = (float*)d_out;
  float* ws = (float*)d_ws;
  unsigned* bar = (unsigned*)((char*)d_ws + BAR_OFF_BYTES);

  hipMemsetAsync(d_ws, 0, WS_CLEAR_BYTES, stream);

  void* args[] = {&ctx, &state, &emb, &ln0w, &ln0b, &ln1w, &ln1b,
                  &amk, &amv, &amr, &tf, &td, &kw, &vw, &rw, &ow,
                  &ln2w, &ln2b, &fmk, &fmr, &fkw, &fvw, &frw,
                  &lnoutw, &lnoutb, &head, &out, &ws, &bar};
  hipLaunchCooperativeKernel((const void*)k_rwkv, dim3(GRID), dim3(BLOCK),
                             args, 0, stream);
}